// Round 13
// baseline (817.850 us; speedup 1.0000x reference)
//
#include <hip/hip_runtime.h>
#include <hip/hip_bf16.h>

// Qwen3 MoE sparse block, MI355X/gfx950.
// Shapes: T=4096 tokens (B2 x S2048), H=2048, I=768, E=16, top-k=8.
// Round 13: BARRIER-FREE wave-private GEMM pipelines. Each wave owns a
// private LDS partition and stages exactly the rows it reads (A/B panels
// duplicated across waves, L2-absorbed). Zero s_barrier; each wave
// free-runs on its own vmcnt ledger (2-buf depth-2, vmcnt(8)/tile).
// Mechanism under test: r5-r12's 8 barrier-synced schedules all plateau
// at ~680 TF; lockstep resync 64x/block is the one untried axis.
// Periphery byte-identical to r12 (617us best).

typedef __attribute__((ext_vector_type(8))) short short8;   // 8 x bf16 (4 VGPRs) MFMA operand
typedef __attribute__((ext_vector_type(4))) float f32x4;    // MFMA accumulator
typedef __attribute__((ext_vector_type(4))) unsigned short us4;

#define NUM_T 4096
#define DH    2048
#define DI    768
#define NE    16
#define DKD   (NE*DI)        // 12288 (dense wdbt row length)
#define MAXMT 20             // gateup m-tiles per expert (capacity 2560 rows)
#define HSC_CAP 2560
#define TOK_HALF 2048
#define FINAL_ELEMS ((size_t)NUM_T*DH)

// ---- helpers -------------------------------------------------------------

static __device__ __forceinline__ unsigned short f2bf(float f) {
  unsigned int u = __builtin_bit_cast(unsigned int, f);
  u += 0x7fffu + ((u >> 16) & 1u);
  return (unsigned short)(u >> 16);
}

static __device__ __forceinline__ float bf2f(unsigned short b) {
  unsigned int u = ((unsigned int)b) << 16;
  return __builtin_bit_cast(float, u);
}

static __device__ __forceinline__ void gload16(const void* g, void* l) {
  __builtin_amdgcn_global_load_lds(
      (__attribute__((address_space(1))) void*)(g),
      (__attribute__((address_space(3))) void*)(l), 16, 0, 0);
}

// ---- kernel 1: hidden fp32 -> bf16 --------------------------------------

__global__ __launch_bounds__(256)
void cvt_hidden_k(const float* __restrict__ in, unsigned short* __restrict__ out) {
  size_t i = (size_t)blockIdx.x * 256 + threadIdx.x;
  const float4* p = (const float4*)in + i * 2;
  float4 a = p[0], b = p[1];
  short8 v;
  v[0] = (short)f2bf(a.x); v[1] = (short)f2bf(a.y);
  v[2] = (short)f2bf(a.z); v[3] = (short)f2bf(a.w);
  v[4] = (short)f2bf(b.x); v[5] = (short)f2bf(b.y);
  v[6] = (short)f2bf(b.z); v[7] = (short)f2bf(b.w);
  *(short8*)(out + i * 8) = v;
}

// ---- kernel 2: transpose + convert, 128x32 tile, ushort4 stores ---------

__global__ __launch_bounds__(256)
void transpose_cvt_k(const float* __restrict__ s0, unsigned short* __restrict__ d0,
                     const float* __restrict__ s1, unsigned short* __restrict__ d1,
                     int C, long inStrideE, long outStrideE, int outLD) {
  __shared__ float tile[128][33];
  const int zz = blockIdx.z, e = zz & 15;
  const float* inE = (zz < 16 ? s0 : s1) + (size_t)e * inStrideE;
  unsigned short* outE = (zz < 16 ? d0 : d1) + (size_t)e * outStrideE;
  const int r0 = blockIdx.x * 128, c0 = blockIdx.y * 32;
  const int tid = threadIdx.x;
  const int lc = tid & 31, rg = tid >> 5;
#pragma unroll
  for (int i = 0; i < 16; i++)
    tile[rg * 16 + i][lc] = inE[(size_t)(r0 + rg * 16 + i) * C + c0 + lc];
  __syncthreads();
  const int u = tid & 31, cg = tid >> 5;
#pragma unroll
  for (int i = 0; i < 4; i++) {
    int c = cg * 4 + i;
    us4 v;
    v[0] = f2bf(tile[u * 4 + 0][c]); v[1] = f2bf(tile[u * 4 + 1][c]);
    v[2] = f2bf(tile[u * 4 + 2][c]); v[3] = f2bf(tile[u * 4 + 3][c]);
    *(us4*)(outE + (size_t)(c0 + c) * outLD + r0 + u * 4) = v;
  }
}

// ---- kernel 3: router + softmax + top-8 + renorm + slot assignment ------

__global__ __launch_bounds__(256)
void router_k(const float* __restrict__ x, const float* __restrict__ wr,
              float* __restrict__ logits_out, unsigned short* __restrict__ dwb,
              unsigned char* __restrict__ slt) {
  int t = blockIdx.x;
  int tid = threadIdx.x, lane = tid & 63, wid = tid >> 6;
  float acc[16];
#pragma unroll
  for (int e = 0; e < 16; e++) acc[e] = 0.f;
  const float* xt = x + (size_t)t * DH;
  for (int i = tid; i < DH; i += 256) {
    float hv = xt[i];
    const float4* w4 = (const float4*)(wr + (size_t)i * 16);
#pragma unroll
    for (int q = 0; q < 4; q++) {
      float4 w = w4[q];
      acc[q * 4 + 0] += hv * w.x; acc[q * 4 + 1] += hv * w.y;
      acc[q * 4 + 2] += hv * w.z; acc[q * 4 + 3] += hv * w.w;
    }
  }
#pragma unroll
  for (int e = 0; e < 16; e++) {
#pragma unroll
    for (int off = 32; off; off >>= 1) acc[e] += __shfl_xor(acc[e], off, 64);
  }
  __shared__ float red[4][16];
  if (lane == 0) {
#pragma unroll
    for (int e = 0; e < 16; e++) red[wid][e] = acc[e];
  }
  __syncthreads();
  if (tid == 0) {
    float lg[16];
#pragma unroll
    for (int e = 0; e < 16; e++) lg[e] = red[0][e] + red[1][e] + red[2][e] + red[3][e];
    float mx = lg[0];
#pragma unroll
    for (int e = 1; e < 16; e++) mx = fmaxf(mx, lg[e]);
    float p[16], s = 0.f;
#pragma unroll
    for (int e = 0; e < 16; e++) { p[e] = __expf(lg[e] - mx); s += p[e]; }
    float inv = 1.f / s;
#pragma unroll
    for (int e = 0; e < 16; e++) p[e] *= inv;
    float tmp[16];
#pragma unroll
    for (int e = 0; e < 16; e++) tmp[e] = p[e];
    int idx[8]; float val[8]; float ts = 0.f;
#pragma unroll
    for (int k = 0; k < 8; k++) {
      int b = 0; float bv = tmp[0];
#pragma unroll
      for (int e = 1; e < 16; e++) { if (tmp[e] > bv) { bv = tmp[e]; b = e; } }
      idx[k] = b; val[k] = bv; tmp[b] = -1.f; ts += bv;
    }
    float dw[16];
    unsigned char sl[16];
#pragma unroll
    for (int e = 0; e < 16; e++) { dw[e] = 0.f; sl[e] = 0xFF; }
    float invt = 1.f / ts;
#pragma unroll
    for (int k = 0; k < 8; k++) { dw[idx[k]] += val[k] * invt; sl[idx[k]] = (unsigned char)k; }
#pragma unroll
    for (int e = 0; e < 16; e++) {
      dwb[(size_t)t * 16 + e] = f2bf(dw[e]);
      slt[(size_t)t * 16 + e] = sl[e];
      logits_out[(size_t)t * 16 + e] = lg[e];
    }
  }
}

// ---- kernel 3b: per-expert compacted token lists + split metadata -------

__global__ __launch_bounds__(256)
void build_lists_k(const unsigned short* __restrict__ dwb,
                   const unsigned char* __restrict__ slt,
                   unsigned short* __restrict__ lst, int* __restrict__ meta) {
  int e = blockIdx.x;
  int tid = threadIdx.x;
  unsigned short loc[16]; int c = 0;
#pragma unroll
  for (int j = 0; j < 16; j++) {
    int t = tid * 16 + j;
    if (dwb[(size_t)t * 16 + e] != 0) {
      unsigned short s = slt[(size_t)t * 16 + e];
      loc[c++] = (unsigned short)(t | (s << 12));
    }
  }
  __shared__ int sc[256];
  __shared__ int pre[257];
  sc[tid] = c;
  __syncthreads();
  if (tid == 0) {
    int s = 0;
    for (int i = 0; i < 256; i++) { pre[i] = s; s += sc[i]; }
    pre[256] = s;
  }
  __syncthreads();
  unsigned short* L = lst + (size_t)e * NUM_T;
  int base = pre[tid];
  for (int j = 0; j < c; j++) L[base + j] = loc[j];
  int total = pre[256];
  for (int i = total + tid; i < NUM_T; i += 256) L[i] = 0xFFFFu;
  if (tid == 0) { meta[e * 2] = pre[128]; meta[e * 2 + 1] = total; }
}

// ---- kernel 4: gateup — barrier-free wave-private pipeline --------------
// Block 128 tokens x 64 I (grid 3840), 4 waves 2m x 2n, per-wave 64x32 per
// matrix. Each wave stages its OWN A rows (4 gloads) + Bg (2) + Bu (2) into
// a private 16KB LDS partition, 2-buf. vmcnt(8) per tile, ZERO barriers.

__global__ __launch_bounds__(256, 2)
void gateup_k(const unsigned short* __restrict__ hbf,
              const unsigned short* __restrict__ wgbt,
              const unsigned short* __restrict__ wubt,
              const unsigned short* __restrict__ dwb,
              const unsigned short* __restrict__ lst,
              unsigned short* __restrict__ hsC) {
  // XCD-bijective swizzle: 3840 = 8 * 480
  const int bxr = blockIdx.x;
  const int wl  = (bxr & 7) * 480 + (bxr >> 3);
  const int e   = wl / 240;                 // 240 = 12 n-groups * 20 m-tiles
  const int rem = wl - e * 240;
  const int n0  = (rem / MAXMT) * 64;
  const int m0  = (rem % MAXMT) * 128;

  const unsigned short* L = lst + (size_t)e * NUM_T;
  if (L[m0] & 0x8000) return;               // tile beyond count[e]

  const int tid = threadIdx.x, lane = tid & 63, wid = tid >> 6;
  const int wm = wid >> 1, wn = wid & 1;
  const int lr = lane & 15, lgp = lane >> 4;

  // wave-private LDS: per wave 2-buf x (A 64x32 + Bg 32x32 + Bu 32x32)
  __shared__ alignas(16) unsigned short As [4 * 2 * 2048];  // 32KB
  __shared__ alignas(16) unsigned short Bgs[4 * 2 * 1024];  // 16KB
  __shared__ alignas(16) unsigned short Bus[4 * 2 * 1024];  // 16KB
  unsigned short* myA = As  + wid * 4096;
  unsigned short* myG = Bgs + wid * 2048;
  unsigned short* myU = Bus + wid * 2048;

  f32x4 zero = {0.f, 0.f, 0.f, 0.f};
  f32x4 accg[4][2], accu[4][2];
#pragma unroll
  for (int m = 0; m < 4; m++)
#pragma unroll
    for (int n = 0; n < 2; n++) { accg[m][n] = zero; accu[m][n] = zero; }

  const unsigned short* wgE = wgbt + (size_t)e * DI * DH;
  const unsigned short* wuE = wubt + (size_t)e * DI * DH;

  const int srow    = lane >> 2;                                   // 0..15
  const int schunk8 = (((lane & 3) - ((lane >> 3) & 3)) & 3) * 8;  // inverse swizzle on src
  const int slot8   = (((lane >> 4) + ((lane >> 1) & 3)) & 3) * 8; // fragment read slot

  // gather bases: this wave's A rows = m0 + wm*64 + i*16 + srow (i=0..3)
  const unsigned short* gA[4];
#pragma unroll
  for (int i = 0; i < 4; i++) {
    unsigned short en = L[m0 + wm * 64 + i * 16 + srow];
    gA[i] = hbf + (size_t)((en & 0x8000) ? 0 : (en & 0xFFF)) * DH + schunk8;
  }
  // this wave's B rows = n0 + wn*32 + i*16 + srow (i=0..1)
  const unsigned short* gG[2];
  const unsigned short* gU[2];
#pragma unroll
  for (int i = 0; i < 2; i++) {
    size_t brow = (size_t)(n0 + wn * 32 + i * 16 + srow);
    gG[i] = wgE + brow * DH + schunk8;
    gU[i] = wuE + brow * DH + schunk8;
  }

  auto stage = [&](int buf, int k0) {        // 8 loads, all wave-private
    unsigned short* Ab = myA + buf * 2048;
    unsigned short* Gb = myG + buf * 1024;
    unsigned short* Ub = myU + buf * 1024;
#pragma unroll
    for (int i = 0; i < 4; i++) gload16(gA[i] + k0, Ab + i * 512);
#pragma unroll
    for (int i = 0; i < 2; i++) {
      gload16(gG[i] + k0, Gb + i * 512);
      gload16(gU[i] + k0, Ub + i * 512);
    }
  };

  auto compute = [&](int buf) {
    const unsigned short* Ab = myA + buf * 2048;
    const unsigned short* Gb = myG + buf * 1024;
    const unsigned short* Ub = myU + buf * 1024;
    short8 a[4], bg[2], bu[2];
#pragma unroll
    for (int m = 0; m < 4; m++)
      a[m] = *(const short8*)(Ab + (m * 16 + lr) * 32 + slot8);
#pragma unroll
    for (int n = 0; n < 2; n++) {
      bg[n] = *(const short8*)(Gb + (n * 16 + lr) * 32 + slot8);
      bu[n] = *(const short8*)(Ub + (n * 16 + lr) * 32 + slot8);
    }
#pragma unroll
    for (int m = 0; m < 4; m++)
#pragma unroll
      for (int n = 0; n < 2; n++) {
        accg[m][n] = __builtin_amdgcn_mfma_f32_16x16x32_bf16(a[m], bg[n], accg[m][n], 0, 0, 0);
        accu[m][n] = __builtin_amdgcn_mfma_f32_16x16x32_bf16(a[m], bu[n], accu[m][n], 0, 0, 0);
      }
  };

  // wave-private 2-buf pipeline, NT = 64 k-tiles, no barriers anywhere
  const int NT = DH / 32;
  stage(0, 0);
  stage(1, 32);
#pragma unroll 1
  for (int i = 0; i < NT - 1; ++i) {
    asm volatile("s_waitcnt vmcnt(8)" ::: "memory");   // tile i's 8 loads done
    __builtin_amdgcn_sched_barrier(0);
    compute(i & 1);
    __builtin_amdgcn_sched_barrier(0);
    if (i + 2 < NT) stage(i & 1, (i + 2) * 32);        // buffer just freed
  }
  asm volatile("s_waitcnt vmcnt(0)" ::: "memory");
  __builtin_amdgcn_sched_barrier(0);
  compute((NT - 1) & 1);

  // epilogue: silu(g)*u * w[t][e] -> bf16 hsC[e][row][i] (per-wave, no sync)
#pragma unroll
  for (int m = 0; m < 4; m++) {
#pragma unroll
    for (int r = 0; r < 4; r++) {
      int mrow = m0 + wm * 64 + m * 16 + 4 * lgp + r;
      unsigned short en = L[mrow];
      if (en & 0x8000) continue;
      int tp = en & 0xFFF;
      float w = bf2f(dwb[(size_t)tp * 16 + e]);
#pragma unroll
      for (int n = 0; n < 2; n++) {
        float g = accg[m][n][r], u = accu[m][n][r];
        float sig = 1.f / (1.f + __expf(-g));
        float val = g * sig * u * w;
        hsC[((size_t)e * HSC_CAP + mrow) * DI + n0 + wn * 32 + n * 16 + lr] = f2bf(val);
      }
    }
  }
}

// ---- kernel 5: down GEMM — barrier-free wave-private pipeline -----------
// Block 128 x 128, 4 waves 2x2, per-wave 64x64. Private 16KB/wave LDS,
// 2-buf, vmcnt(8)/tile, zero barriers. NT = 24.

__global__ __launch_bounds__(256, 2)
void down_half_k(const unsigned short* __restrict__ hsC,
                 const unsigned short* __restrict__ wdbt,
                 const unsigned short* __restrict__ lst,
                 const int* __restrict__ meta,
                 unsigned short* __restrict__ slotbuf, int hf) {
  const int bxr = blockIdx.x;
  const int wl  = (bxr & 7) * 320 + (bxr >> 3);
  const int e   = wl / 160;
  const int rem = wl - e * 160;
  const int n0  = (rem / 10) * 128;
  const int m0  = (rem % 10) * 128;

  const int rs = hf ? meta[e * 2] : 0;
  const int re = hf ? meta[e * 2 + 1] : meta[e * 2];
  const int rcount = re - rs;
  if (m0 >= rcount) return;

  const int tid = threadIdx.x, lane = tid & 63, wid = tid >> 6;
  const int wm = wid >> 1, wn = wid & 1;
  const int lr = lane & 15, lgp = lane >> 4;

  __shared__ alignas(16) unsigned short As[4 * 2 * 2048];  // 32KB
  __shared__ alignas(16) unsigned short Bs[4 * 2 * 2048];  // 32KB
  unsigned short* myA = As + wid * 4096;
  unsigned short* myB = Bs + wid * 4096;

  f32x4 zero = {0.f, 0.f, 0.f, 0.f};
  f32x4 acc[4][4];
#pragma unroll
  for (int m = 0; m < 4; m++)
#pragma unroll
    for (int n = 0; n < 4; n++) acc[m][n] = zero;

  const int srow    = lane >> 2;
  const int schunk8 = (((lane & 3) - ((lane >> 3) & 3)) & 3) * 8;
  const int slot8   = (((lane >> 4) + ((lane >> 1) & 3)) & 3) * 8;

  const unsigned short* wdE = wdbt + (size_t)e * DI;

  // this wave's A rows: hsC rows e*HSC_CAP + rs + m0 + wm*64 + i*16 + srow
  const unsigned short* gA[4];
  const unsigned short* gB[4];
#pragma unroll
  for (int i = 0; i < 4; i++) {
    size_t arow = (size_t)(e * HSC_CAP + rs + m0 + wm * 64 + i * 16 + srow);
    gA[i] = hsC + arow * DI + schunk8;
    size_t brow = (size_t)(n0 + wn * 64 + i * 16 + srow);
    gB[i] = wdE + brow * DKD + schunk8;
  }

  auto stage = [&](int buf, int k0) {        // 8 loads, wave-private
    unsigned short* Ab = myA + buf * 2048;
    unsigned short* Bb = myB + buf * 2048;
#pragma unroll
    for (int i = 0; i < 4; i++) {
      gload16(gA[i] + k0, Ab + i * 512);
      gload16(gB[i] + k0, Bb + i * 512);
    }
  };

  auto compute = [&](int buf) {
    const unsigned short* Ab = myA + buf * 2048;
    const unsigned short* Bb = myB + buf * 2048;
    short8 a[4], b[4];
#pragma unroll
    for (int m = 0; m < 4; m++)
      a[m] = *(const short8*)(Ab + (m * 16 + lr) * 32 + slot8);
#pragma unroll
    for (int n = 0; n < 4; n++)
      b[n] = *(const short8*)(Bb + (n * 16 + lr) * 32 + slot8);
#pragma unroll
    for (int m = 0; m < 4; m++)
#pragma unroll
      for (int n = 0; n < 4; n++)
        acc[m][n] = __builtin_amdgcn_mfma_f32_16x16x32_bf16(a[m], b[n], acc[m][n], 0, 0, 0);
  };

  const int NT = DI / 32;                   // 24
  stage(0, 0);
  stage(1, 32);
#pragma unroll 1
  for (int i = 0; i < NT - 1; ++i) {
    asm volatile("s_waitcnt vmcnt(8)" ::: "memory");
    __builtin_amdgcn_sched_barrier(0);
    compute(i & 1);
    __builtin_amdgcn_sched_barrier(0);
    if (i + 2 < NT) stage(i & 1, (i + 2) * 32);
  }
  asm volatile("s_waitcnt vmcnt(0)" ::: "memory");
  __builtin_amdgcn_sched_barrier(0);
  compute((NT - 1) & 1);

  const unsigned short* L = lst + (size_t)e * NUM_T;
#pragma unroll
  for (int m = 0; m < 4; m++) {
#pragma unroll
    for (int r = 0; r < 4; r++) {
      int gr = m0 + wm * 64 + m * 16 + 4 * lgp + r;
      if (gr >= rcount) continue;
      unsigned short en = L[rs + gr];
      int t  = en & 0xFFF;
      int s  = (en >> 12) & 7;
      int tl = t - hf * TOK_HALF;
#pragma unroll
      for (int n = 0; n < 4; n++)
        slotbuf[((size_t)s * TOK_HALF + tl) * DH + n0 + wn * 64 + n * 16 + lr] =
            f2bf(acc[m][n][r]);
    }
  }
}

// ---- kernel 6: reduce 8 slots -> final fp32 output (one token half) -----

__global__ __launch_bounds__(256)
void reduce_half_k(const unsigned short* __restrict__ slotbuf,
                   float* __restrict__ outp, int hf) {
  size_t i  = (size_t)blockIdx.x * 256 + threadIdx.x;
  size_t tl = i >> 8;
  size_t h0 = (i & 255) * 8;
  float sum[8];
#pragma unroll
  for (int j = 0; j < 8; j++) sum[j] = 0.f;
#pragma unroll
  for (int s = 0; s < 8; s++) {
    short8 v = *(const short8*)(slotbuf + ((size_t)s * TOK_HALF + tl) * DH + h0);
#pragma unroll
    for (int j = 0; j < 8; j++) sum[j] += bf2f((unsigned short)v[j]);
  }
  float* o = outp + ((size_t)(hf * TOK_HALF) + tl) * DH + h0;
  float4 o0 = {sum[0], sum[1], sum[2], sum[3]};
  float4 o1 = {sum[4], sum[5], sum[6], sum[7]};
  *(float4*)o = o0;
  *(float4*)(o + 4) = o1;
}

// ---- launch --------------------------------------------------------------

extern "C" void kernel_launch(void* const* d_in, const int* in_sizes, int n_in,
                              void* d_out, int out_size, void* d_ws, size_t ws_size,
                              hipStream_t stream) {
  const float* x  = (const float*)d_in[0];   // [2,2048,2048]
  const float* wr = (const float*)d_in[1];   // [2048,16]
  const float* wg = (const float*)d_in[2];   // [16,2048,768]
  const float* wu = (const float*)d_in[3];   // [16,2048,768]
  const float* wd = (const float*)d_in[4];   // [16,768,2048]

  float* outF = (float*)d_out;               // final [T][H]
  float* outL = outF + FINAL_ELEMS;          // router logits [T][E]

  // workspace layout (bytes), total 180,682,880 (r6 layout):
  //   hbf   @ 0          : 16,777,216   bf16 hidden [T][H]     (dead after gateup)
  //   wubt  @ 16,777,216 : 50,331,648   bf16 up B^T [E][I][H]  (dead after gateup)
  //   hsC   @ 67,108,864 : 62,914,560   bf16 compacted h [E][2560][I]
  //   wgbt  @ 130,023,424: 50,331,648   bf16 gate B^T; reused as wdbt [H][E*I]
  //   dwb   @ 180,355,072: 131,072      bf16 combine weights [T][E]
  //   lst   @ 180,486,144: 131,072      u16 lists [E][T]: t | slot<<12
  //   slt   @ 180,617,216: 65,536       u8 slot table [T][E]
  //   meta  @ 180,682,752: 128          i32 {half0_count, total} per expert
  //   slotbuf @ 0 (aliases hbf+wubt): 67,108,864  bf16 [8][2048][H]
  if (ws_size < 180682880ull) return;
  char* ws = (char*)d_ws;
  unsigned short* hbf   = (unsigned short*)(ws);
  unsigned short* wubt  = (unsigned short*)(ws + 16777216);
  unsigned short* hsC   = (unsigned short*)(ws + 67108864);
  unsigned short* wgbt  = (unsigned short*)(ws + 130023424);
  unsigned short* dwb   = (unsigned short*)(ws + 180355072);
  unsigned short* lst   = (unsigned short*)(ws + 180486144);
  unsigned char*  slt   = (unsigned char*) (ws + 180617216);
  int*            meta  = (int*)           (ws + 180682752);
  unsigned short* sbuf  = (unsigned short*)(ws);            // after gateup
  unsigned short* wdbt  = wgbt;                             // after gateup

  cvt_hidden_k<<<4096, 256, 0, stream>>>(x, hbf);
  // gate+up transpose merged: per expert in [2048][768] -> B^T [768][2048]
  transpose_cvt_k<<<dim3(16, 24, 32), 256, 0, stream>>>(
      wg, wgbt, wu, wubt, 768, (long)2048 * 768, (long)768 * 2048, 2048);
  router_k<<<4096, 256, 0, stream>>>(x, wr, outL, dwb, slt);
  build_lists_k<<<16, 256, 0, stream>>>(dwb, slt, lst, meta);
  gateup_k<<<3840, 256, 0, stream>>>(hbf, wgbt, wubt, dwb, lst, hsC);
  // wd transpose: per expert in [768][2048] -> wdbt[h][e*768 + i]
  transpose_cvt_k<<<dim3(6, 64, 16), 256, 0, stream>>>(
      wd, wdbt, wd, wdbt, 2048, (long)768 * 2048, 768L, 12288);
  down_half_k<<<2560, 256, 0, stream>>>(hsC, wdbt, lst, meta, sbuf, 0);
  reduce_half_k<<<2048, 256, 0, stream>>>(sbuf, outF, 0);
  down_half_k<<<2560, 256, 0, stream>>>(hsC, wdbt, lst, meta, sbuf, 1);
  reduce_half_k<<<2048, 256, 0, stream>>>(sbuf, outF, 1);
}

// Round 14
// 603.477 us; speedup vs baseline: 1.3552x; 1.3552x over previous
//
#include <hip/hip_runtime.h>
#include <hip/hip_bf16.h>

// Qwen3 MoE sparse block, MI355X/gfx950.
// Shapes: T=4096 tokens (B2 x S2048), H=2048, I=768, E=16, top-k=8.
// Round 14: consolidation to best-known. GEMMs = r12 exactly (616.9us best:
// gateup 128x128 3-stage counted-vmcnt(6) issue-early, 2 blk/CU; down
// 128x128 3-stage vmcnt(4), 3 blk/CU; 10 schedule variants confirmed this
// is the local optimum). One periphery win: x->bf16 convert fused into the
// UNCHANGED strided router loop (adds one coalesced 2B/lane store per
// iteration; r10's failure was restructuring the loop, not the fusion).

typedef __attribute__((ext_vector_type(8))) short short8;   // 8 x bf16 (4 VGPRs) MFMA operand
typedef __attribute__((ext_vector_type(4))) float f32x4;    // MFMA accumulator
typedef __attribute__((ext_vector_type(4))) unsigned short us4;

#define NUM_T 4096
#define DH    2048
#define DI    768
#define NE    16
#define DKD   (NE*DI)        // 12288 (dense wdbt row length)
#define MAXMT 20             // gateup m-tiles per expert (capacity 2560 rows)
#define HSC_CAP 2560
#define TOK_HALF 2048
#define FINAL_ELEMS ((size_t)NUM_T*DH)

// ---- helpers -------------------------------------------------------------

static __device__ __forceinline__ unsigned short f2bf(float f) {
  unsigned int u = __builtin_bit_cast(unsigned int, f);
  u += 0x7fffu + ((u >> 16) & 1u);
  return (unsigned short)(u >> 16);
}

static __device__ __forceinline__ float bf2f(unsigned short b) {
  unsigned int u = ((unsigned int)b) << 16;
  return __builtin_bit_cast(float, u);
}

static __device__ __forceinline__ void gload16(const void* g, void* l) {
  __builtin_amdgcn_global_load_lds(
      (__attribute__((address_space(1))) void*)(g),
      (__attribute__((address_space(3))) void*)(l), 16, 0, 0);
}

// ---- kernel 2: transpose + convert, 128x32 tile, ushort4 stores ---------
// in: [R][C] fp32 per expert; out[c][r] bf16 (row length outLD).
// Dual-source: blockIdx.z < 16 -> (s0,d0), else (s1,d1).

__global__ __launch_bounds__(256)
void transpose_cvt_k(const float* __restrict__ s0, unsigned short* __restrict__ d0,
                     const float* __restrict__ s1, unsigned short* __restrict__ d1,
                     int C, long inStrideE, long outStrideE, int outLD) {
  __shared__ float tile[128][33];
  const int zz = blockIdx.z, e = zz & 15;
  const float* inE = (zz < 16 ? s0 : s1) + (size_t)e * inStrideE;
  unsigned short* outE = (zz < 16 ? d0 : d1) + (size_t)e * outStrideE;
  const int r0 = blockIdx.x * 128, c0 = blockIdx.y * 32;
  const int tid = threadIdx.x;
  const int lc = tid & 31, rg = tid >> 5;
#pragma unroll
  for (int i = 0; i < 16; i++)
    tile[rg * 16 + i][lc] = inE[(size_t)(r0 + rg * 16 + i) * C + c0 + lc];
  __syncthreads();
  const int u = tid & 31, cg = tid >> 5;
#pragma unroll
  for (int i = 0; i < 4; i++) {
    int c = cg * 4 + i;
    us4 v;
    v[0] = f2bf(tile[u * 4 + 0][c]); v[1] = f2bf(tile[u * 4 + 1][c]);
    v[2] = f2bf(tile[u * 4 + 2][c]); v[3] = f2bf(tile[u * 4 + 3][c]);
    *(us4*)(outE + (size_t)(c0 + c) * outLD + r0 + u * 4) = v;
  }
}

// ---- kernel 3: router + fused x->bf16 (strided loop unchanged) ----------

__global__ __launch_bounds__(256)
void router_k(const float* __restrict__ x, const float* __restrict__ wr,
              float* __restrict__ logits_out, unsigned short* __restrict__ dwb,
              unsigned char* __restrict__ slt, unsigned short* __restrict__ hbf) {
  int t = blockIdx.x;
  int tid = threadIdx.x, lane = tid & 63, wid = tid >> 6;
  float acc[16];
#pragma unroll
  for (int e = 0; e < 16; e++) acc[e] = 0.f;
  const float* xt = x + (size_t)t * DH;
  unsigned short* ht = hbf + (size_t)t * DH;
  for (int i = tid; i < DH; i += 256) {
    float hv = xt[i];
    ht[i] = f2bf(hv);                       // fused bf16 copy (coalesced)
    const float4* w4 = (const float4*)(wr + (size_t)i * 16);
#pragma unroll
    for (int q = 0; q < 4; q++) {
      float4 w = w4[q];
      acc[q * 4 + 0] += hv * w.x; acc[q * 4 + 1] += hv * w.y;
      acc[q * 4 + 2] += hv * w.z; acc[q * 4 + 3] += hv * w.w;
    }
  }
#pragma unroll
  for (int e = 0; e < 16; e++) {
#pragma unroll
    for (int off = 32; off; off >>= 1) acc[e] += __shfl_xor(acc[e], off, 64);
  }
  __shared__ float red[4][16];
  if (lane == 0) {
#pragma unroll
    for (int e = 0; e < 16; e++) red[wid][e] = acc[e];
  }
  __syncthreads();
  if (tid == 0) {
    float lg[16];
#pragma unroll
    for (int e = 0; e < 16; e++) lg[e] = red[0][e] + red[1][e] + red[2][e] + red[3][e];
    float mx = lg[0];
#pragma unroll
    for (int e = 1; e < 16; e++) mx = fmaxf(mx, lg[e]);
    float p[16], s = 0.f;
#pragma unroll
    for (int e = 0; e < 16; e++) { p[e] = __expf(lg[e] - mx); s += p[e]; }
    float inv = 1.f / s;
#pragma unroll
    for (int e = 0; e < 16; e++) p[e] *= inv;
    float tmp[16];
#pragma unroll
    for (int e = 0; e < 16; e++) tmp[e] = p[e];
    int idx[8]; float val[8]; float ts = 0.f;
#pragma unroll
    for (int k = 0; k < 8; k++) {
      int b = 0; float bv = tmp[0];
#pragma unroll
      for (int e = 1; e < 16; e++) { if (tmp[e] > bv) { bv = tmp[e]; b = e; } }
      idx[k] = b; val[k] = bv; tmp[b] = -1.f; ts += bv;
    }
    float dw[16];
    unsigned char sl[16];
#pragma unroll
    for (int e = 0; e < 16; e++) { dw[e] = 0.f; sl[e] = 0xFF; }
    float invt = 1.f / ts;
#pragma unroll
    for (int k = 0; k < 8; k++) { dw[idx[k]] += val[k] * invt; sl[idx[k]] = (unsigned char)k; }
#pragma unroll
    for (int e = 0; e < 16; e++) {
      dwb[(size_t)t * 16 + e] = f2bf(dw[e]);
      slt[(size_t)t * 16 + e] = sl[e];
      logits_out[(size_t)t * 16 + e] = lg[e];
    }
  }
}

// ---- kernel 3b: per-expert compacted token lists + split metadata -------

__global__ __launch_bounds__(256)
void build_lists_k(const unsigned short* __restrict__ dwb,
                   const unsigned char* __restrict__ slt,
                   unsigned short* __restrict__ lst, int* __restrict__ meta) {
  int e = blockIdx.x;
  int tid = threadIdx.x;
  unsigned short loc[16]; int c = 0;
#pragma unroll
  for (int j = 0; j < 16; j++) {
    int t = tid * 16 + j;
    if (dwb[(size_t)t * 16 + e] != 0) {
      unsigned short s = slt[(size_t)t * 16 + e];
      loc[c++] = (unsigned short)(t | (s << 12));
    }
  }
  __shared__ int sc[256];
  __shared__ int pre[257];
  sc[tid] = c;
  __syncthreads();
  if (tid == 0) {
    int s = 0;
    for (int i = 0; i < 256; i++) { pre[i] = s; s += sc[i]; }
    pre[256] = s;
  }
  __syncthreads();
  unsigned short* L = lst + (size_t)e * NUM_T;
  int base = pre[tid];
  for (int j = 0; j < c; j++) L[base + j] = loc[j];
  int total = pre[256];
  for (int i = total + tid; i < NUM_T; i += 256) L[i] = 0xFFFFu;
  if (tid == 0) { meta[e * 2] = pre[128]; meta[e * 2 + 1] = total; }
}

// ---- kernel 4: gateup, 128x128 tile, 3-stage counted-vmcnt(6) (r12) -----
// 4 waves (2m x 2n), per-wave 64x64 per matrix (accg[4][4]+accu[4][4]).
// LDS 3-buf x 24KB = 72KB -> 2 blocks/CU. 6 gloads/wave/tile, vmcnt(6),
// issue-early stage.

__global__ __launch_bounds__(256, 2)
void gateup_k(const unsigned short* __restrict__ hbf,
              const unsigned short* __restrict__ wgbt,
              const unsigned short* __restrict__ wubt,
              const unsigned short* __restrict__ dwb,
              const unsigned short* __restrict__ lst,
              unsigned short* __restrict__ hsC) {
  // XCD-bijective swizzle: 1920 = 8 * 240; e-major -> n-group(6) -> mtile(20)
  const int bxr = blockIdx.x;
  const int wl  = (bxr & 7) * 240 + (bxr >> 3);
  const int e   = wl / 120;                 // 120 = 6 n-groups * 20 m-tiles
  const int rem = wl - e * 120;
  const int n0  = (rem / MAXMT) * 128;
  const int m0  = (rem % MAXMT) * 128;

  const unsigned short* L = lst + (size_t)e * NUM_T;
  if (L[m0] & 0x8000) return;               // tile beyond count[e]

  const int tid = threadIdx.x, lane = tid & 63, wid = tid >> 6;
  const int wm = wid >> 1, wn = wid & 1;
  const int lr = lane & 15, lgp = lane >> 4;

  __shared__ alignas(16) unsigned short As [3 * 128 * 32];  // 24KB
  __shared__ alignas(16) unsigned short Bgs[3 * 128 * 32];  // 24KB
  __shared__ alignas(16) unsigned short Bus[3 * 128 * 32];  // 24KB

  f32x4 zero = {0.f, 0.f, 0.f, 0.f};
  f32x4 accg[4][4], accu[4][4];
#pragma unroll
  for (int m = 0; m < 4; m++)
#pragma unroll
    for (int n = 0; n < 4; n++) { accg[m][n] = zero; accu[m][n] = zero; }

  const unsigned short* wgE = wgbt + (size_t)e * DI * DH;
  const unsigned short* wuE = wubt + (size_t)e * DI * DH;

  const int srow    = lane >> 2;                                   // 0..15
  const int schunk8 = (((lane & 3) - ((lane >> 3) & 3)) & 3) * 8;  // inverse swizzle on src

  const int ar0 = m0 + wid * 32 + srow, ar1 = ar0 + 16;
  const unsigned short t0 = L[ar0], t1 = L[ar1];
  const size_t prow0 = (t0 & 0x8000) ? 0 : (size_t)(t0 & 0xFFF);
  const size_t prow1 = (t1 & 0x8000) ? 0 : (size_t)(t1 & 0xFFF);
  const size_t brow0 = (size_t)(n0 + wid * 32 + srow), brow1 = brow0 + 16;

  const int slot8 = (((lane >> 4) + ((lane >> 1) & 3)) & 3) * 8;   // fragment read slot

  auto stage = [&](int b, int k0) {           // 6 loads per wave
    unsigned short* Ab = As  + b * 4096 + wid * 1024;
    unsigned short* Gb = Bgs + b * 4096 + wid * 1024;
    unsigned short* Ub = Bus + b * 4096 + wid * 1024;
    gload16(hbf + prow0 * DH + k0 + schunk8, Ab);
    gload16(hbf + prow1 * DH + k0 + schunk8, Ab + 512);
    gload16(wgE + brow0 * DH + k0 + schunk8, Gb);
    gload16(wgE + brow1 * DH + k0 + schunk8, Gb + 512);
    gload16(wuE + brow0 * DH + k0 + schunk8, Ub);
    gload16(wuE + brow1 * DH + k0 + schunk8, Ub + 512);
  };

  auto compute = [&](int b) {
    const unsigned short* Ab = As  + b * 4096;
    const unsigned short* Gb = Bgs + b * 4096;
    const unsigned short* Ub = Bus + b * 4096;
    short8 a[4], bg[4], bu[4];
#pragma unroll
    for (int m = 0; m < 4; m++)
      a[m] = *(const short8*)(Ab + (wm * 64 + m * 16 + lr) * 32 + slot8);
#pragma unroll
    for (int n = 0; n < 4; n++) {
      bg[n] = *(const short8*)(Gb + (wn * 64 + n * 16 + lr) * 32 + slot8);
      bu[n] = *(const short8*)(Ub + (wn * 64 + n * 16 + lr) * 32 + slot8);
    }
#pragma unroll
    for (int m = 0; m < 4; m++)
#pragma unroll
      for (int n = 0; n < 4; n++) {
        accg[m][n] = __builtin_amdgcn_mfma_f32_16x16x32_bf16(a[m], bg[n], accg[m][n], 0, 0, 0);
        accu[m][n] = __builtin_amdgcn_mfma_f32_16x16x32_bf16(a[m], bu[n], accu[m][n], 0, 0, 0);
      }
  };

  // 3-stage pipeline over NT = 64 k-tiles; stage for i+2 issued before
  // compute of i (issue-early). vmcnt(6) = newest tile's 6 loads in flight.
  const int NT = DH / 32;
  stage(0, 0);
  stage(1, 32);
  int bc = 0, bs = 2;
#pragma unroll 1
  for (int i = 0; i < NT - 1; ++i) {
    asm volatile("s_waitcnt vmcnt(6)" ::: "memory");   // tile i complete
    __builtin_amdgcn_s_barrier();
    __builtin_amdgcn_sched_barrier(0);
    if (i + 2 < NT) stage(bs, (i + 2) * 32);
    compute(bc);
    bc = (bc == 2) ? 0 : bc + 1;
    bs = (bs == 2) ? 0 : bs + 1;
  }
  asm volatile("s_waitcnt vmcnt(0)" ::: "memory");
  __builtin_amdgcn_s_barrier();
  __builtin_amdgcn_sched_barrier(0);
  compute(bc);

  // epilogue: silu(g)*u * w[t][e] -> bf16 hsC[e][row][i] (compacted rows)
#pragma unroll
  for (int m = 0; m < 4; m++) {
#pragma unroll
    for (int r = 0; r < 4; r++) {
      int mrow = m0 + wm * 64 + m * 16 + 4 * lgp + r;
      unsigned short en = L[mrow];
      if (en & 0x8000) continue;
      int tp = en & 0xFFF;
      float w = bf2f(dwb[(size_t)tp * 16 + e]);
#pragma unroll
      for (int n = 0; n < 4; n++) {
        float g = accg[m][n][r], u = accu[m][n][r];
        float sig = 1.f / (1.f + __expf(-g));
        float val = g * sig * u * w;
        hsC[((size_t)e * HSC_CAP + mrow) * DI + n0 + wn * 64 + n * 16 + lr] = f2bf(val);
      }
    }
  }
}

// ---- kernel 5: per-expert down GEMM (half of tokens) -> slot buffer -----
// r6 structure + issue-early stage (r11/r12-proven).

__global__ __launch_bounds__(256, 3)
void down_half_k(const unsigned short* __restrict__ hsC,
                 const unsigned short* __restrict__ wdbt,
                 const unsigned short* __restrict__ lst,
                 const int* __restrict__ meta,
                 unsigned short* __restrict__ slotbuf, int hf) {
  const int bxr = blockIdx.x;
  const int wl  = (bxr & 7) * 320 + (bxr >> 3);
  const int e   = wl / 160;
  const int rem = wl - e * 160;
  const int n0  = (rem / 10) * 128;
  const int m0  = (rem % 10) * 128;

  const int rs = hf ? meta[e * 2] : 0;
  const int re = hf ? meta[e * 2 + 1] : meta[e * 2];
  const int rcount = re - rs;
  if (m0 >= rcount) return;

  const int tid = threadIdx.x, lane = tid & 63, wid = tid >> 6;
  const int wm = wid >> 1, wn = wid & 1;
  const int lr = lane & 15, lgp = lane >> 4;

  __shared__ alignas(16) unsigned short As[3 * 128 * 32];
  __shared__ alignas(16) unsigned short Bs[3 * 128 * 32];

  f32x4 zero = {0.f, 0.f, 0.f, 0.f};
  f32x4 acc[4][4];
#pragma unroll
  for (int m = 0; m < 4; m++)
#pragma unroll
    for (int n = 0; n < 4; n++) acc[m][n] = zero;

  const int srow    = lane >> 2;
  const int schunk8 = (((lane & 3) - ((lane >> 3) & 3)) & 3) * 8;
  const int sOff0   = wid * 1024;
  const int sOff1   = sOff0 + 512;
  const size_t arow0 = (size_t)(e * HSC_CAP + rs + m0 + wid * 32 + srow);
  const size_t arow1 = arow0 + 16;
  const size_t brow0 = (size_t)(n0 + wid * 32 + srow), brow1 = brow0 + 16;
  const int slot8 = (((lane >> 4) + ((lane >> 1) & 3)) & 3) * 8;

  const unsigned short* wdE = wdbt + (size_t)e * DI;

  auto stage = [&](int b, int k0) {
    unsigned short* Ab = As + b * 4096;
    unsigned short* Bb = Bs + b * 4096;
    gload16(hsC + arow0 * DI + k0 + schunk8, Ab + sOff0);
    gload16(hsC + arow1 * DI + k0 + schunk8, Ab + sOff1);
    gload16(wdE + brow0 * DKD + k0 + schunk8, Bb + sOff0);
    gload16(wdE + brow1 * DKD + k0 + schunk8, Bb + sOff1);
  };

  auto compute = [&](int bsel) {
    const unsigned short* Ab = As + bsel * 4096;
    const unsigned short* Bb = Bs + bsel * 4096;
    short8 a[4], b[4];
#pragma unroll
    for (int m = 0; m < 4; m++)
      a[m] = *(const short8*)(Ab + (size_t)(wm * 64 + m * 16 + lr) * 32 + slot8);
#pragma unroll
    for (int n = 0; n < 4; n++)
      b[n] = *(const short8*)(Bb + (size_t)(wn * 64 + n * 16 + lr) * 32 + slot8);
#pragma unroll
    for (int m = 0; m < 4; m++)
#pragma unroll
      for (int n = 0; n < 4; n++)
        acc[m][n] = __builtin_amdgcn_mfma_f32_16x16x32_bf16(a[m], b[n], acc[m][n], 0, 0, 0);
  };

  const int NT = DI / 32;                   // 24
  stage(0, 0);
  stage(1, 32);
  int bc = 0, bs = 2;
#pragma unroll 1
  for (int i = 0; i < NT - 1; ++i) {
    asm volatile("s_waitcnt vmcnt(4)" ::: "memory");
    __builtin_amdgcn_s_barrier();
    __builtin_amdgcn_sched_barrier(0);
    if (i + 2 < NT) stage(bs, (i + 2) * 32);
    compute(bc);
    bc = (bc == 2) ? 0 : bc + 1;
    bs = (bs == 2) ? 0 : bs + 1;
  }
  asm volatile("s_waitcnt vmcnt(0)" ::: "memory");
  __builtin_amdgcn_s_barrier();
  __builtin_amdgcn_sched_barrier(0);
  compute(bc);

  const unsigned short* L = lst + (size_t)e * NUM_T;
#pragma unroll
  for (int m = 0; m < 4; m++) {
#pragma unroll
    for (int r = 0; r < 4; r++) {
      int gr = m0 + wm * 64 + m * 16 + 4 * lgp + r;
      if (gr >= rcount) continue;
      unsigned short en = L[rs + gr];
      int t  = en & 0xFFF;
      int s  = (en >> 12) & 7;
      int tl = t - hf * TOK_HALF;
#pragma unroll
      for (int n = 0; n < 4; n++)
        slotbuf[((size_t)s * TOK_HALF + tl) * DH + n0 + wn * 64 + n * 16 + lr] =
            f2bf(acc[m][n][r]);
    }
  }
}

// ---- kernel 6: reduce 8 slots -> final fp32 output (one token half) -----

__global__ __launch_bounds__(256)
void reduce_half_k(const unsigned short* __restrict__ slotbuf,
                   float* __restrict__ outp, int hf) {
  size_t i  = (size_t)blockIdx.x * 256 + threadIdx.x;
  size_t tl = i >> 8;
  size_t h0 = (i & 255) * 8;
  float sum[8];
#pragma unroll
  for (int j = 0; j < 8; j++) sum[j] = 0.f;
#pragma unroll
  for (int s = 0; s < 8; s++) {
    short8 v = *(const short8*)(slotbuf + ((size_t)s * TOK_HALF + tl) * DH + h0);
#pragma unroll
    for (int j = 0; j < 8; j++) sum[j] += bf2f((unsigned short)v[j]);
  }
  float* o = outp + ((size_t)(hf * TOK_HALF) + tl) * DH + h0;
  float4 o0 = {sum[0], sum[1], sum[2], sum[3]};
  float4 o1 = {sum[4], sum[5], sum[6], sum[7]};
  *(float4*)o = o0;
  *(float4*)(o + 4) = o1;
}

// ---- launch --------------------------------------------------------------

extern "C" void kernel_launch(void* const* d_in, const int* in_sizes, int n_in,
                              void* d_out, int out_size, void* d_ws, size_t ws_size,
                              hipStream_t stream) {
  const float* x  = (const float*)d_in[0];   // [2,2048,2048]
  const float* wr = (const float*)d_in[1];   // [2048,16]
  const float* wg = (const float*)d_in[2];   // [16,2048,768]
  const float* wu = (const float*)d_in[3];   // [16,2048,768]
  const float* wd = (const float*)d_in[4];   // [16,768,2048]

  float* outF = (float*)d_out;               // final [T][H]
  float* outL = outF + FINAL_ELEMS;          // router logits [T][E]

  // workspace layout (bytes), total 180,682,880 (r6 layout):
  //   hbf   @ 0          : 16,777,216   bf16 hidden [T][H]     (dead after gateup)
  //   wubt  @ 16,777,216 : 50,331,648   bf16 up B^T [E][I][H]  (dead after gateup)
  //   hsC   @ 67,108,864 : 62,914,560   bf16 compacted h [E][2560][I]
  //   wgbt  @ 130,023,424: 50,331,648   bf16 gate B^T; reused as wdbt [H][E*I]
  //   dwb   @ 180,355,072: 131,072      bf16 combine weights [T][E]
  //   lst   @ 180,486,144: 131,072      u16 lists [E][T]: t | slot<<12
  //   slt   @ 180,617,216: 65,536       u8 slot table [T][E]
  //   meta  @ 180,682,752: 128          i32 {half0_count, total} per expert
  //   slotbuf @ 0 (aliases hbf+wubt): 67,108,864  bf16 [8][2048][H]
  if (ws_size < 180682880ull) return;
  char* ws = (char*)d_ws;
  unsigned short* hbf   = (unsigned short*)(ws);
  unsigned short* wubt  = (unsigned short*)(ws + 16777216);
  unsigned short* hsC   = (unsigned short*)(ws + 67108864);
  unsigned short* wgbt  = (unsigned short*)(ws + 130023424);
  unsigned short* dwb   = (unsigned short*)(ws + 180355072);
  unsigned short* lst   = (unsigned short*)(ws + 180486144);
  unsigned char*  slt   = (unsigned char*) (ws + 180617216);
  int*            meta  = (int*)           (ws + 180682752);
  unsigned short* sbuf  = (unsigned short*)(ws);            // after gateup
  unsigned short* wdbt  = wgbt;                             // after gateup

  // router with fused x -> bf16 hidden copy
  router_k<<<4096, 256, 0, stream>>>(x, wr, outL, dwb, slt, hbf);
  build_lists_k<<<16, 256, 0, stream>>>(dwb, slt, lst, meta);
  // gate+up transpose merged: per expert in [2048][768] -> B^T [768][2048]
  transpose_cvt_k<<<dim3(16, 24, 32), 256, 0, stream>>>(
      wg, wgbt, wu, wubt, 768, (long)2048 * 768, (long)768 * 2048, 2048);
  gateup_k<<<1920, 256, 0, stream>>>(hbf, wgbt, wubt, dwb, lst, hsC);
  // wd transpose: per expert in [768][2048] -> wdbt[h][e*768 + i]
  transpose_cvt_k<<<dim3(6, 64, 16), 256, 0, stream>>>(
      wd, wdbt, wd, wdbt, 2048, (long)768 * 2048, 768L, 12288);
  down_half_k<<<2560, 256, 0, stream>>>(hsC, wdbt, lst, meta, sbuf, 0);
  reduce_half_k<<<2048, 256, 0, stream>>>(sbuf, outF, 0);
  down_half_k<<<2560, 256, 0, stream>>>(hsC, wdbt, lst, meta, sbuf, 1);
  reduce_half_k<<<2048, 256, 0, stream>>>(sbuf, outF, 1);
}